// Round 1
// baseline (318.622 us; speedup 1.0000x reference)
//
#include <hip/hip_runtime.h>
#include <math.h>

#define Bc 64
#define Nc 4
#define Ac 1024
#define Oc 128
#define Dc 256
#define Qc 256
#define Hc 128
#define BN (Bc*Nc)

using f4 = __attribute__((ext_vector_type(4))) float;

__device__ inline float decode_t(const void* p) {
    // t is a Python scalar 1 -> could be int32/int64 (first 4 bytes == 1) or float32
    int i = *(const int*)p;
    if (i >= 1 && i <= 1000000) return (float)i;
    return __int_as_float(i);
}

// ---------------------------------------------------------------------------
// prep_M: M[b] = obj_reps[b] (128x256) @ W1v (256x128)
// grid (2,2,64): 64x64 tile per block, 256 threads, 4x4 register block
// ---------------------------------------------------------------------------
__global__ __launch_bounds__(256) void prep_M_kernel(
    const float* __restrict__ obj, const float* __restrict__ W1,
    float* __restrict__ Mmat)
{
    __shared__ float obj_sT[32][68];  // k-major (transposed), pad for banks, stride%4==0
    __shared__ float w_s[32][68];

    const int t = threadIdx.x;
    const int tx = t & 15;        // h sub: h = h0 + tx*4 + j
    const int ty = t >> 4;        // o sub: o = o0 + ty*4 + i
    const int h0 = blockIdx.x * 64;
    const int o0 = blockIdx.y * 64;
    const int b  = blockIdx.z;

    float acc[4][4];
    #pragma unroll
    for (int i = 0; i < 4; i++)
        #pragma unroll
        for (int j = 0; j < 4; j++) acc[i][j] = 0.f;

    const float* ob = obj + (size_t)(b * Oc + o0) * Dc;

    for (int ko = 0; ko < 8; ++ko) {
        __syncthreads();
        // stage obj tile 64(o) x 32(d), transposed into obj_sT[d][o]
        #pragma unroll
        for (int s = 0; s < 2; s++) {
            int idx = t + 256 * s;
            int r = idx >> 3, c4 = idx & 7;
            f4 v = *(const f4*)(ob + (size_t)r * Dc + ko * 32 + c4 * 4);
            obj_sT[c4 * 4 + 0][r] = v[0];
            obj_sT[c4 * 4 + 1][r] = v[1];
            obj_sT[c4 * 4 + 2][r] = v[2];
            obj_sT[c4 * 4 + 3][r] = v[3];
        }
        // stage W1 tile 32(d) x 64(h), k-major already
        #pragma unroll
        for (int s = 0; s < 2; s++) {
            int idx = t + 256 * s;
            int r = idx >> 4, c4 = idx & 15;
            f4 v = *(const f4*)(W1 + (size_t)(ko * 32 + r) * Hc + h0 + c4 * 4);
            *(f4*)&w_s[r][c4 * 4] = v;
        }
        __syncthreads();
        #pragma unroll 4
        for (int k = 0; k < 32; k++) {
            f4 af = *(const f4*)&obj_sT[k][ty * 4];
            f4 bf = *(const f4*)&w_s[k][tx * 4];
            #pragma unroll
            for (int i = 0; i < 4; i++)
                #pragma unroll
                for (int j = 0; j < 4; j++)
                    acc[i][j] += af[i] * bf[j];
        }
    }

    float* mout = Mmat + (size_t)b * Oc * Hc;
    #pragma unroll
    for (int i = 0; i < 4; i++)
        #pragma unroll
        for (int j = 0; j < 4; j++)
            mout[(size_t)(o0 + ty * 4 + i) * Hc + h0 + tx * 4 + j] = acc[i][j];
}

// ---------------------------------------------------------------------------
// prep_qb: qb[bn,h] = q[bn,:] @ W1q + b1[h]; also zero-init out_acc and Z
// grid (256), 128 threads
// ---------------------------------------------------------------------------
__global__ __launch_bounds__(128) void prep_qb_kernel(
    const float* __restrict__ q, const float* __restrict__ W1,
    const float* __restrict__ b1, float* __restrict__ qb,
    float* __restrict__ out_acc, float* __restrict__ Zsum)
{
    __shared__ float qs[256];
    const int t = threadIdx.x;
    const int bn = blockIdx.x;

    qs[t]       = q[bn * Qc + t];
    qs[t + 128] = q[bn * Qc + 128 + t];
    __syncthreads();

    float acc = b1[t];
    const float* w = W1 + (size_t)Dc * Hc + t;   // W1q, column t
    #pragma unroll 8
    for (int d = 0; d < 256; ++d)
        acc += qs[d] * w[(size_t)d * Hc];

    qb[bn * Hc + t] = acc;
    out_acc[bn * Oc + t] = 0.f;   // Oc == Hc == 128
    if (t == 0) Zsum[bn] = 0.f;
}

// ---------------------------------------------------------------------------
// main: per (b,n,a-tile of 64):
//   preact(64x128) = att1_tile(64x128) @ M[b](128x128) + qb
//   logits = relu(preact) @ W2 + b2 ; e = tag>0 ? exp(logit/t) : 0
//   atomic: Z[bn] += sum e ; out_acc[bn,o] += sum_a e_a * att1[a,o]
// grid (16, 4, 64), 256 threads
// ---------------------------------------------------------------------------
__global__ __launch_bounds__(256) void main_kernel(
    const float* __restrict__ att1, const int* __restrict__ tags,
    const float* __restrict__ Mmat, const float* __restrict__ qb,
    const float* __restrict__ W2, const float* __restrict__ b2,
    const void* __restrict__ tptr,
    float* __restrict__ out_acc, float* __restrict__ Zsum)
{
    __shared__ float att_sT[32][68];   // k-major att tile (k x a), stride%4==0
    __shared__ float m_s[32][132];     // k x h (128), padded
    __shared__ float part_s[64][17];
    __shared__ float e_s[64];

    const int t  = threadIdx.x;
    const int tx = t & 15;     // h group: h = tx*8 .. tx*8+7
    const int ty = t >> 4;     // a group: a = ty*4 .. ty*4+3
    const int a0 = blockIdx.x * 64;
    const int n  = blockIdx.y;
    const int b  = blockIdx.z;
    const int bn = b * Nc + n;

    float acc[4][8];
    #pragma unroll
    for (int i = 0; i < 4; i++)
        #pragma unroll
        for (int j = 0; j < 8; j++) acc[i][j] = 0.f;

    const float* att_base = att1 + (size_t)(bn * Ac + a0) * Oc;
    const float* M_base   = Mmat + (size_t)b * Oc * Hc;

    for (int ko = 0; ko < 4; ++ko) {
        __syncthreads();
        // stage att tile 64(a) x 32(o), transposed into att_sT[o][a]
        #pragma unroll
        for (int s = 0; s < 2; s++) {
            int idx = t + 256 * s;
            int r = idx >> 3, c4 = idx & 7;
            f4 v = *(const f4*)(att_base + (size_t)r * Oc + ko * 32 + c4 * 4);
            att_sT[c4 * 4 + 0][r] = v[0];
            att_sT[c4 * 4 + 1][r] = v[1];
            att_sT[c4 * 4 + 2][r] = v[2];
            att_sT[c4 * 4 + 3][r] = v[3];
        }
        // stage M tile 32(o) x 128(h)
        #pragma unroll
        for (int s = 0; s < 4; s++) {
            int idx = t + 256 * s;
            int r = idx >> 5, c4 = idx & 31;
            f4 v = *(const f4*)(M_base + (size_t)(ko * 32 + r) * Hc + c4 * 4);
            *(f4*)&m_s[r][c4 * 4] = v;
        }
        __syncthreads();
        #pragma unroll 4
        for (int k = 0; k < 32; k++) {
            f4 af  = *(const f4*)&att_sT[k][ty * 4];
            f4 bf0 = *(const f4*)&m_s[k][tx * 8];
            f4 bf1 = *(const f4*)&m_s[k][tx * 8 + 4];
            #pragma unroll
            for (int i = 0; i < 4; i++) {
                #pragma unroll
                for (int j = 0; j < 4; j++) {
                    acc[i][j]     += af[i] * bf0[j];
                    acc[i][j + 4] += af[i] * bf1[j];
                }
            }
        }
    }

    // epilogue: + qb, relu, dot W2 -> per-(a, tx) partial
    float qbv[8], w2v[8];
    #pragma unroll
    for (int j = 0; j < 8; j++) {
        qbv[j] = qb[bn * Hc + tx * 8 + j];
        w2v[j] = W2[tx * 8 + j];
    }
    #pragma unroll
    for (int i = 0; i < 4; i++) {
        float p = 0.f;
        #pragma unroll
        for (int j = 0; j < 8; j++) {
            float v = acc[i][j] + qbv[j];
            v = v > 0.f ? v : 0.f;
            p += v * w2v[j];
        }
        part_s[ty * 4 + i][tx] = p;
    }
    __syncthreads();

    if (t < 64) {   // wave 0: one thread per token
        float sum = 0.f;
        #pragma unroll
        for (int x = 0; x < 16; x++) sum += part_s[t][x];
        float tval = decode_t(tptr);
        float logit = (sum + b2[0]) / tval;
        int tag = tags[bn * Ac + a0 + t];
        float e = (tag > 0) ? expf(logit) : 0.f;
        e_s[t] = e;
        float zs = e;
        #pragma unroll
        for (int off = 32; off > 0; off >>= 1) zs += __shfl_down(zs, off);
        if (t == 0) atomicAdd(&Zsum[bn], zs);
    }
    __syncthreads();

    // phase 3: out_acc[bn,o] += sum_a e[a] * att1[a,o]  (tile is L2-hot)
    const int o = t & 127;
    const int half = t >> 7;
    const float* ab = att_base + (size_t)(half * 32) * Oc + o;
    float accum = 0.f;
    #pragma unroll 8
    for (int a = 0; a < 32; a++)
        accum += e_s[half * 32 + a] * ab[(size_t)a * Oc];
    atomicAdd(&out_acc[bn * Oc + o], accum);
}

// ---------------------------------------------------------------------------
__global__ void finalize_kernel(const float* __restrict__ out_acc,
                                const float* __restrict__ Zsum,
                                float* __restrict__ out)
{
    int idx = blockIdx.x * 256 + threadIdx.x;
    if (idx < BN * Oc) {
        out[idx] = out_acc[idx] / Zsum[idx >> 7];
    }
}

extern "C" void kernel_launch(void* const* d_in, const int* in_sizes, int n_in,
                              void* d_out, int out_size, void* d_ws, size_t ws_size,
                              hipStream_t stream)
{
    (void)in_sizes; (void)n_in; (void)out_size; (void)ws_size;

    const float* q    = (const float*)d_in[0];
    const float* att1 = (const float*)d_in[1];
    const float* obj  = (const float*)d_in[2];
    const int*   tags = (const int*)d_in[3];
    const float* W1   = (const float*)d_in[4];
    const float* b1   = (const float*)d_in[5];
    const float* W2   = (const float*)d_in[6];
    const float* b2   = (const float*)d_in[7];
    const void*  tptr = d_in[8];
    float* out = (float*)d_out;

    float* ws   = (float*)d_ws;
    float* Mmat = ws;                                 // B*O*H   = 1,048,576 floats
    float* qb   = Mmat + (size_t)Bc * Oc * Hc;        // BN*H    = 32,768
    float* oacc = qb + (size_t)BN * Hc;               // BN*O    = 32,768
    float* Zs   = oacc + (size_t)BN * Oc;             // BN      = 256

    prep_M_kernel<<<dim3(2, 2, Bc), 256, 0, stream>>>(obj, W1, Mmat);
    prep_qb_kernel<<<dim3(BN), 128, 0, stream>>>(q, W1, b1, qb, oacc, Zs);
    main_kernel<<<dim3(Ac / 64, Nc, Bc), 256, 0, stream>>>(att1, tags, Mmat, qb,
                                                           W2, b2, tptr, oacc, Zs);
    finalize_kernel<<<dim3(BN * Oc / 256), 256, 0, stream>>>(oacc, Zs, out);
}

// Round 2
// 267.458 us; speedup vs baseline: 1.1913x; 1.1913x over previous
//
#include <hip/hip_runtime.h>
#include <math.h>

#define Bc 64
#define Nc 4
#define Ac 1024
#define Oc 128
#define Dc 256
#define Qc 256
#define Hc 128
#define BN (Bc*Nc)

using f4     = __attribute__((ext_vector_type(4))) float;
using f32x4  = __attribute__((ext_vector_type(4))) float;
using short8 = __attribute__((ext_vector_type(8))) short;
using us4    = __attribute__((ext_vector_type(4))) unsigned short;

__device__ inline float decode_t(const void* p) {
    int i = *(const int*)p;
    if (i >= 1 && i <= 1000000) return (float)i;
    return __int_as_float(i);
}

// split fp32 -> truncated bf16 hi + bf16(residual) lo.  x ~= hi + lo, err ~2^-16
__device__ inline void split_bf16(float x, unsigned short& hi, unsigned short& lo) {
    unsigned u = __builtin_bit_cast(unsigned, x);
    hi = (unsigned short)(u >> 16);
    float hif = __builtin_bit_cast(float, u & 0xFFFF0000u);
    float lof = x - hif;
    lo = (unsigned short)(__builtin_bit_cast(unsigned, lof) >> 16);
}

// ---------------------------------------------------------------------------
// prep_M: Mt[b][h][o] = sum_d W1[d][h] * obj[b][o][d]   (M transposed, [n][k])
// output as bf16 hi/lo pair.  grid (4,2,64): 32h x 64o tile, 256 thr, 2x4 reg
// ---------------------------------------------------------------------------
__global__ __launch_bounds__(256) void prep_M_kernel(
    const float* __restrict__ obj, const float* __restrict__ W1,
    unsigned short* __restrict__ Mt_hi, unsigned short* __restrict__ Mt_lo)
{
    __shared__ float w_s[32][36];     // [k][h]  (W1 rows are h-major: no transpose)
    __shared__ float obj_sT[32][68];  // [k][o]  (transposed from obj rows)

    const int t  = threadIdx.x;
    const int tx = t & 15;    // o = o0 + tx*4 + j
    const int ty = t >> 4;    // h = h0 + ty*2 + i
    const int h0 = blockIdx.x * 32;
    const int o0 = blockIdx.y * 64;
    const int b  = blockIdx.z;

    float acc[2][4];
    #pragma unroll
    for (int i = 0; i < 2; i++)
        #pragma unroll
        for (int j = 0; j < 4; j++) acc[i][j] = 0.f;

    for (int ko = 0; ko < 8; ++ko) {
        __syncthreads();
        // W1 slice rows d=k0..k0+31, cols h0..h0+31 : 1024 floats, 1 f4/thread
        {
            int r = t >> 3, c4 = t & 7;
            f4 v = *(const f4*)(W1 + (size_t)(ko * 32 + r) * Hc + h0 + c4 * 4);
            *(f4*)&w_s[r][c4 * 4] = v;
        }
        // obj slice rows o0..o0+63, cols d=k0..k0+31, transposed
        #pragma unroll
        for (int s = 0; s < 2; s++) {
            int idx = t + 256 * s;
            int r = idx >> 3, c4 = idx & 7;
            f4 v = *(const f4*)(obj + ((size_t)b * Oc + o0 + r) * Dc + ko * 32 + c4 * 4);
            obj_sT[c4 * 4 + 0][r] = v[0];
            obj_sT[c4 * 4 + 1][r] = v[1];
            obj_sT[c4 * 4 + 2][r] = v[2];
            obj_sT[c4 * 4 + 3][r] = v[3];
        }
        __syncthreads();
        #pragma unroll 4
        for (int k = 0; k < 32; k++) {
            float a0 = w_s[k][ty * 2];
            float a1 = w_s[k][ty * 2 + 1];
            f4 bv = *(const f4*)&obj_sT[k][tx * 4];
            #pragma unroll
            for (int j = 0; j < 4; j++) {
                acc[0][j] += a0 * bv[j];
                acc[1][j] += a1 * bv[j];
            }
        }
    }

    #pragma unroll
    for (int i = 0; i < 2; i++) {
        us4 hi, lo;
        #pragma unroll
        for (int j = 0; j < 4; j++) {
            unsigned short h16, l16;
            split_bf16(acc[i][j], h16, l16);
            hi[j] = h16; lo[j] = l16;
        }
        size_t ofs = ((size_t)b * Hc + h0 + ty * 2 + i) * Oc + o0 + tx * 4;
        *(us4*)(Mt_hi + ofs) = hi;
        *(us4*)(Mt_lo + ofs) = lo;
    }
}

// ---------------------------------------------------------------------------
// prep_qb: qb[bn,h] = q[bn,:] @ W1q + b1[h]; zero-init out_acc and Z
// grid (256), 512 threads: 4-way K-split + LDS reduce
// ---------------------------------------------------------------------------
__global__ __launch_bounds__(512) void prep_qb_kernel(
    const float* __restrict__ q, const float* __restrict__ W1,
    const float* __restrict__ b1, float* __restrict__ qb,
    float* __restrict__ out_acc, float* __restrict__ Zsum)
{
    __shared__ float qs[256];
    __shared__ float red[4][128];
    const int t = threadIdx.x;
    const int bn = blockIdx.x;

    if (t < 256) qs[t] = q[bn * Qc + t];
    __syncthreads();

    const int h = t & 127, kq = t >> 7;
    float acc = 0.f;
    const float* w = W1 + (size_t)(Dc + kq * 64) * Hc + h;
    #pragma unroll 8
    for (int d = 0; d < 64; ++d)
        acc += qs[kq * 64 + d] * w[(size_t)d * Hc];
    red[kq][h] = acc;
    __syncthreads();

    if (t < 128) {
        qb[bn * Hc + t] = b1[t] + red[0][t] + red[1][t] + red[2][t] + red[3][t];
        out_acc[bn * Oc + t] = 0.f;
    }
    if (t == 128) Zsum[bn] = 0.f;
}

// ---------------------------------------------------------------------------
// main: per (b,n,a-tile of 64):
//   preact(64x128) = att_tile @ M[b] via split-bf16 MFMA (3 products)
//   logits = relu(preact+qb) @ W2 + b2 ; e = tag>0 ? exp(logit/t) : 0
//   atomic: Z[bn] += sum e ; out_acc[bn,o] += sum_a e_a * att1[a,o]
// grid (16, 4, 64), 256 threads = 4 waves; wave w covers all 64 a, h=w*32..+31
// ---------------------------------------------------------------------------
__global__ __launch_bounds__(256) void main_kernel(
    const float* __restrict__ att1, const int* __restrict__ tags,
    const unsigned short* __restrict__ Mt_hi, const unsigned short* __restrict__ Mt_lo,
    const float* __restrict__ qb, const float* __restrict__ W2,
    const float* __restrict__ b2, const void* __restrict__ tptr,
    float* __restrict__ out_acc, float* __restrict__ Zsum)
{
    __shared__ unsigned short A_hi[64][136];   // [a][o] bf16, +8 pad (16B)
    __shared__ unsigned short A_lo[64][136];
    __shared__ float part2[64][4];
    __shared__ float qb_s[128], w2_s[128];
    __shared__ float e_s[64];

    const int t    = threadIdx.x;
    const int wave = t >> 6;
    const int lane = t & 63;
    const int l15  = lane & 15;
    const int quad = lane >> 4;
    const int a0 = blockIdx.x * 64;
    const int n  = blockIdx.y;
    const int b  = blockIdx.z;
    const int bn = b * Nc + n;

    const float* att_base = att1 + ((size_t)bn * Ac + a0) * Oc;

    // ---- stage att tile 64x128 fp32 -> bf16 hi/lo in LDS ----
    #pragma unroll
    for (int s = 0; s < 8; s++) {
        int idx = t + 256 * s;
        int r = idx >> 5, c4 = idx & 31;
        f4 v = *(const f4*)(att_base + (size_t)r * Oc + c4 * 4);
        us4 hi, lo;
        #pragma unroll
        for (int j = 0; j < 4; j++) {
            unsigned short h16, l16;
            split_bf16(v[j], h16, l16);
            hi[j] = h16; lo[j] = l16;
        }
        *(us4*)&A_hi[r][c4 * 4] = hi;
        *(us4*)&A_lo[r][c4 * 4] = lo;
    }
    if (t < 128) { qb_s[t] = qb[bn * Hc + t]; w2_s[t] = W2[t]; }
    __syncthreads();

    // ---- MFMA: acc[i][j] covers m = i*16.., n(h) = wave*32 + j*16.. ----
    f32x4 acc[4][2];
    #pragma unroll
    for (int i = 0; i < 4; i++)
        #pragma unroll
        for (int j = 0; j < 2; j++) acc[i][j] = (f32x4)(0.f);

    const unsigned short* BhiB = Mt_hi + ((size_t)b * Hc + wave * 32 + l15) * Oc;
    const unsigned short* BloB = Mt_lo + ((size_t)b * Hc + wave * 32 + l15) * Oc;
    const int kq8 = quad * 8;

    #pragma unroll
    for (int ks = 0; ks < 4; ks++) {
        const int ko = ks * 32 + kq8;
        short8 b0h = *(const short8*)(BhiB + ko);
        short8 b0l = *(const short8*)(BloB + ko);
        short8 b1h = *(const short8*)(BhiB + 16 * Oc + ko);
        short8 b1l = *(const short8*)(BloB + 16 * Oc + ko);
        #pragma unroll
        for (int i = 0; i < 4; i++) {
            short8 ah = *(const short8*)&A_hi[i * 16 + l15][ko];
            short8 al = *(const short8*)&A_lo[i * 16 + l15][ko];
            acc[i][0] = __builtin_amdgcn_mfma_f32_16x16x32_bf16(ah, b0h, acc[i][0], 0, 0, 0);
            acc[i][0] = __builtin_amdgcn_mfma_f32_16x16x32_bf16(al, b0h, acc[i][0], 0, 0, 0);
            acc[i][0] = __builtin_amdgcn_mfma_f32_16x16x32_bf16(ah, b0l, acc[i][0], 0, 0, 0);
            acc[i][1] = __builtin_amdgcn_mfma_f32_16x16x32_bf16(ah, b1h, acc[i][1], 0, 0, 0);
            acc[i][1] = __builtin_amdgcn_mfma_f32_16x16x32_bf16(al, b1h, acc[i][1], 0, 0, 0);
            acc[i][1] = __builtin_amdgcn_mfma_f32_16x16x32_bf16(ah, b1l, acc[i][1], 0, 0, 0);
        }
    }

    // ---- epilogue: +qb, relu, *W2, reduce over h ----
    // C/D layout: col(h) = l15, row(a) = i*16 + quad*4 + reg
    float p[4][4];
    #pragma unroll
    for (int i = 0; i < 4; i++)
        #pragma unroll
        for (int r = 0; r < 4; r++) p[i][r] = 0.f;
    #pragma unroll
    for (int j = 0; j < 2; j++) {
        int h = wave * 32 + j * 16 + l15;
        float qbv = qb_s[h], w2v = w2_s[h];
        #pragma unroll
        for (int i = 0; i < 4; i++)
            #pragma unroll
            for (int r = 0; r < 4; r++) {
                float v = acc[i][j][r] + qbv;
                v = v > 0.f ? v : 0.f;
                p[i][r] += v * w2v;
            }
    }
    #pragma unroll
    for (int m = 1; m <= 8; m <<= 1)
        #pragma unroll
        for (int i = 0; i < 4; i++)
            #pragma unroll
            for (int r = 0; r < 4; r++)
                p[i][r] += __shfl_xor(p[i][r], m);
    if (l15 == 0) {
        #pragma unroll
        for (int i = 0; i < 4; i++)
            #pragma unroll
            for (int r = 0; r < 4; r++)
                part2[i * 16 + quad * 4 + r][wave] = p[i][r];
    }
    __syncthreads();

    // ---- softmax numerator ----
    if (t < 64) {
        float sum = part2[t][0] + part2[t][1] + part2[t][2] + part2[t][3] + b2[0];
        float tval = decode_t(tptr);
        float logit = sum / tval;
        int tag = tags[bn * Ac + a0 + t];
        float e = (tag > 0) ? expf(logit) : 0.f;
        e_s[t] = e;
        float zs = e;
        #pragma unroll
        for (int off = 32; off > 0; off >>= 1) zs += __shfl_down(zs, off);
        if (t == 0) atomicAdd(&Zsum[bn], zs);
    }
    __syncthreads();

    // ---- phase 3: out_acc[bn,o] += sum_a e[a] * att1[a,o]  (L2/L3-hot) ----
    const int o = t & 127;
    const int half = t >> 7;
    const float* ab = att_base + (size_t)(half * 32) * Oc + o;
    float accum = 0.f;
    #pragma unroll 8
    for (int a = 0; a < 32; a++)
        accum += e_s[half * 32 + a] * ab[(size_t)a * Oc];
    atomicAdd(&out_acc[bn * Oc + o], accum);
}

// ---------------------------------------------------------------------------
__global__ void finalize_kernel(const float* __restrict__ out_acc,
                                const float* __restrict__ Zsum,
                                float* __restrict__ out)
{
    int idx = blockIdx.x * 256 + threadIdx.x;
    if (idx < BN * Oc) {
        out[idx] = out_acc[idx] / Zsum[idx >> 7];
    }
}

extern "C" void kernel_launch(void* const* d_in, const int* in_sizes, int n_in,
                              void* d_out, int out_size, void* d_ws, size_t ws_size,
                              hipStream_t stream)
{
    (void)in_sizes; (void)n_in; (void)out_size; (void)ws_size;

    const float* q    = (const float*)d_in[0];
    const float* att1 = (const float*)d_in[1];
    const float* obj  = (const float*)d_in[2];
    const int*   tags = (const int*)d_in[3];
    const float* W1   = (const float*)d_in[4];
    const float* b1   = (const float*)d_in[5];
    const float* W2   = (const float*)d_in[6];
    const float* b2   = (const float*)d_in[7];
    const void*  tptr = d_in[8];
    float* out = (float*)d_out;

    char* wsb = (char*)d_ws;
    unsigned short* Mt_hi = (unsigned short*)wsb;                          // 2 MB
    unsigned short* Mt_lo = (unsigned short*)(wsb + (size_t)2*1024*1024);  // 2 MB
    float* qbuf = (float*)(wsb + (size_t)4*1024*1024);   // BN*H  = 32768 floats
    float* oacc = qbuf + (size_t)BN * Hc;                // BN*O  = 32768
    float* Zs   = oacc + (size_t)BN * Oc;                // BN    = 256

    prep_M_kernel<<<dim3(4, 2, Bc), 256, 0, stream>>>(obj, W1, Mt_hi, Mt_lo);
    prep_qb_kernel<<<dim3(BN), 512, 0, stream>>>(q, W1, b1, qbuf, oacc, Zs);
    main_kernel<<<dim3(Ac / 64, Nc, Bc), 256, 0, stream>>>(att1, tags, Mt_hi, Mt_lo,
                                                           qbuf, W2, b2, tptr, oacc, Zs);
    finalize_kernel<<<dim3(BN * Oc / 256), 256, 0, stream>>>(oacc, Zs, out);
}

// Round 3
// 254.567 us; speedup vs baseline: 1.2516x; 1.0506x over previous
//
#include <hip/hip_runtime.h>
#include <math.h>

#define Bc 64
#define Nc 4
#define Ac 1024
#define Oc 128
#define Dc 256
#define Qc 256
#define Hc 128
#define BN (Bc*Nc)

using f4     = __attribute__((ext_vector_type(4))) float;
using f32x4  = __attribute__((ext_vector_type(4))) float;
using short8 = __attribute__((ext_vector_type(8))) short;
using us4    = __attribute__((ext_vector_type(4))) unsigned short;

__device__ inline float decode_t(const void* p) {
    int i = *(const int*)p;
    if (i >= 1 && i <= 1000000) return (float)i;
    return __int_as_float(i);
}

// split fp32 -> truncated bf16 hi + bf16(residual) lo.  x ~= hi + lo, err ~2^-16
__device__ inline void split_bf16(float x, unsigned short& hi, unsigned short& lo) {
    unsigned u = __builtin_bit_cast(unsigned, x);
    hi = (unsigned short)(u >> 16);
    float hif = __builtin_bit_cast(float, u & 0xFFFF0000u);
    float lof = x - hif;
    lo = (unsigned short)(__builtin_bit_cast(unsigned, lof) >> 16);
}

// ---------------------------------------------------------------------------
// prep_M: Mt[b][h][o] = sum_d W1[d][h] * obj[b][o][d]   (M transposed, [n][k])
// output as bf16 hi/lo pair.  grid (4,2,64): 32h x 64o tile, 256 thr, 2x4 reg
// ---------------------------------------------------------------------------
__global__ __launch_bounds__(256) void prep_M_kernel(
    const float* __restrict__ obj, const float* __restrict__ W1,
    unsigned short* __restrict__ Mt_hi, unsigned short* __restrict__ Mt_lo)
{
    __shared__ float w_s[32][36];     // [k][h]
    __shared__ float obj_sT[32][68];  // [k][o]

    const int t  = threadIdx.x;
    const int tx = t & 15;    // o = o0 + tx*4 + j
    const int ty = t >> 4;    // h = h0 + ty*2 + i
    const int h0 = blockIdx.x * 32;
    const int o0 = blockIdx.y * 64;
    const int b  = blockIdx.z;

    float acc[2][4];
    #pragma unroll
    for (int i = 0; i < 2; i++)
        #pragma unroll
        for (int j = 0; j < 4; j++) acc[i][j] = 0.f;

    for (int ko = 0; ko < 8; ++ko) {
        __syncthreads();
        // issue all loads first (latency overlap)
        f4 wv, ov0, ov1;
        {
            int r = t >> 3, c4 = t & 7;
            wv = *(const f4*)(W1 + (size_t)(ko * 32 + r) * Hc + h0 + c4 * 4);
        }
        {
            int r0 = t >> 3, c40 = t & 7;
            ov0 = *(const f4*)(obj + ((size_t)b * Oc + o0 + r0) * Dc + ko * 32 + c40 * 4);
            int idx = t + 256;
            int r1 = idx >> 3, c41 = idx & 7;
            ov1 = *(const f4*)(obj + ((size_t)b * Oc + o0 + r1) * Dc + ko * 32 + c41 * 4);
        }
        {
            int r = t >> 3, c4 = t & 7;
            *(f4*)&w_s[r][c4 * 4] = wv;
            obj_sT[c4 * 4 + 0][r] = ov0[0];
            obj_sT[c4 * 4 + 1][r] = ov0[1];
            obj_sT[c4 * 4 + 2][r] = ov0[2];
            obj_sT[c4 * 4 + 3][r] = ov0[3];
            int idx = t + 256;
            int r1 = idx >> 3, c41 = idx & 7;
            obj_sT[c41 * 4 + 0][r1] = ov1[0];
            obj_sT[c41 * 4 + 1][r1] = ov1[1];
            obj_sT[c41 * 4 + 2][r1] = ov1[2];
            obj_sT[c41 * 4 + 3][r1] = ov1[3];
        }
        __syncthreads();
        #pragma unroll 4
        for (int k = 0; k < 32; k++) {
            float a0 = w_s[k][ty * 2];
            float a1 = w_s[k][ty * 2 + 1];
            f4 bv = *(const f4*)&obj_sT[k][tx * 4];
            #pragma unroll
            for (int j = 0; j < 4; j++) {
                acc[0][j] += a0 * bv[j];
                acc[1][j] += a1 * bv[j];
            }
        }
    }

    #pragma unroll
    for (int i = 0; i < 2; i++) {
        us4 hi, lo;
        #pragma unroll
        for (int j = 0; j < 4; j++) {
            unsigned short h16, l16;
            split_bf16(acc[i][j], h16, l16);
            hi[j] = h16; lo[j] = l16;
        }
        size_t ofs = ((size_t)b * Hc + h0 + ty * 2 + i) * Oc + o0 + tx * 4;
        *(us4*)(Mt_hi + ofs) = hi;
        *(us4*)(Mt_lo + ofs) = lo;
    }
}

// ---------------------------------------------------------------------------
// prep_qb: qb[bn,h] = q[bn,:] @ W1q + b1[h]; zero-init out_acc and Z
// grid (256), 512 threads: 4-way K-split + LDS reduce
// ---------------------------------------------------------------------------
__global__ __launch_bounds__(512) void prep_qb_kernel(
    const float* __restrict__ q, const float* __restrict__ W1,
    const float* __restrict__ b1, float* __restrict__ qb,
    float* __restrict__ out_acc, float* __restrict__ Zsum)
{
    __shared__ float qs[256];
    __shared__ float red[4][128];
    const int t = threadIdx.x;
    const int bn = blockIdx.x;

    if (t < 256) qs[t] = q[bn * Qc + t];
    __syncthreads();

    const int h = t & 127, kq = t >> 7;
    float acc = 0.f;
    const float* w = W1 + (size_t)(Dc + kq * 64) * Hc + h;
    #pragma unroll 8
    for (int d = 0; d < 64; ++d)
        acc += qs[kq * 64 + d] * w[(size_t)d * Hc];
    red[kq][h] = acc;
    __syncthreads();

    if (t < 128) {
        qb[bn * Hc + t] = b1[t] + red[0][t] + red[1][t] + red[2][t] + red[3][t];
        out_acc[bn * Oc + t] = 0.f;
    }
    if (t == 128) Zsum[bn] = 0.f;
}

// ---------------------------------------------------------------------------
// main: per (b,n,a-tile of 64):
//   preact(64x128) = att_tile @ M[b] via split-bf16 MFMA (3 products)
//   logits = relu(preact+qb) @ W2 + b2 ; e = tag>0 ? exp(logit/t) : 0
//   atomic: Z[bn] += sum e ; out_acc[bn,o] += sum_a e_a * att1[a,o]
// grid (16, 4, 64), 256 threads = 4 waves; wave w covers all 64 a, h=w*32..+31
// All 24 global loads (8 staging f4 + 16 B short8) issued up front, in flight
// together; MFMA K-loop is pure LDS+MFMA (B held in registers).
// ---------------------------------------------------------------------------
__global__ __launch_bounds__(256, 4) void main_kernel(
    const float* __restrict__ att1, const int* __restrict__ tags,
    const unsigned short* __restrict__ Mt_hi, const unsigned short* __restrict__ Mt_lo,
    const float* __restrict__ qb, const float* __restrict__ W2,
    const float* __restrict__ b2, const void* __restrict__ tptr,
    float* __restrict__ out_acc, float* __restrict__ Zsum)
{
    __shared__ unsigned short A_hi[64][136];   // [a][o] bf16, stride 272B (16B-mult)
    __shared__ unsigned short A_lo[64][136];
    __shared__ float part2[64][4];
    __shared__ float qb_s[128], w2_s[128];
    __shared__ float e_s[64];

    const int t    = threadIdx.x;
    const int wave = t >> 6;
    const int lane = t & 63;
    const int l15  = lane & 15;
    const int quad = lane >> 4;
    const int a0 = blockIdx.x * 64;
    const int n  = blockIdx.y;
    const int b  = blockIdx.z;
    const int bn = b * Nc + n;

    const float* att_base = att1 + ((size_t)bn * Ac + a0) * Oc;

    // ---- issue ALL staging loads (HBM) ----
    f4 sv[8];
    #pragma unroll
    for (int s = 0; s < 8; s++) {
        int idx = t + 256 * s;
        sv[s] = *(const f4*)(att_base + (size_t)(idx >> 5) * Oc + (idx & 31) * 4);
    }

    // ---- issue ALL B-fragment loads (L2-hot Mt) ----
    const unsigned short* BhiB = Mt_hi + ((size_t)b * Hc + wave * 32 + l15) * Oc;
    const unsigned short* BloB = Mt_lo + ((size_t)b * Hc + wave * 32 + l15) * Oc;
    short8 Bh[4][2], Bl[4][2];
    #pragma unroll
    for (int ks = 0; ks < 4; ks++) {
        const int ko = ks * 32 + quad * 8;
        Bh[ks][0] = *(const short8*)(BhiB + ko);
        Bh[ks][1] = *(const short8*)(BhiB + 16 * Oc + ko);
        Bl[ks][0] = *(const short8*)(BloB + ko);
        Bl[ks][1] = *(const short8*)(BloB + 16 * Oc + ko);
    }

    // ---- small epilogue operands, also in flight ----
    if (t < 128) { qb_s[t] = qb[bn * Hc + t]; w2_s[t] = W2[t]; }
    const int mytag = (t < 64) ? tags[bn * Ac + a0 + t] : 0;
    const float b2v = b2[0];
    const float tval = decode_t(tptr);

    // ---- convert staging regs -> bf16 hi/lo in LDS ----
    #pragma unroll
    for (int s = 0; s < 8; s++) {
        int idx = t + 256 * s;
        int r = idx >> 5, c4 = idx & 31;
        us4 hi, lo;
        #pragma unroll
        for (int j = 0; j < 4; j++) {
            unsigned short h16, l16;
            split_bf16(sv[s][j], h16, l16);
            hi[j] = h16; lo[j] = l16;
        }
        *(us4*)&A_hi[r][c4 * 4] = hi;
        *(us4*)&A_lo[r][c4 * 4] = lo;
    }
    __syncthreads();

    // ---- MFMA: pure LDS + MFMA, B in registers ----
    f32x4 acc[4][2];
    #pragma unroll
    for (int i = 0; i < 4; i++)
        #pragma unroll
        for (int j = 0; j < 2; j++) acc[i][j] = (f32x4)(0.f);

    #pragma unroll
    for (int ks = 0; ks < 4; ks++) {
        const int ko = ks * 32 + quad * 8;
        #pragma unroll
        for (int i = 0; i < 4; i++) {
            short8 ah = *(const short8*)&A_hi[i * 16 + l15][ko];
            short8 al = *(const short8*)&A_lo[i * 16 + l15][ko];
            acc[i][0] = __builtin_amdgcn_mfma_f32_16x16x32_bf16(ah, Bh[ks][0], acc[i][0], 0, 0, 0);
            acc[i][0] = __builtin_amdgcn_mfma_f32_16x16x32_bf16(al, Bh[ks][0], acc[i][0], 0, 0, 0);
            acc[i][0] = __builtin_amdgcn_mfma_f32_16x16x32_bf16(ah, Bl[ks][0], acc[i][0], 0, 0, 0);
            acc[i][1] = __builtin_amdgcn_mfma_f32_16x16x32_bf16(ah, Bh[ks][1], acc[i][1], 0, 0, 0);
            acc[i][1] = __builtin_amdgcn_mfma_f32_16x16x32_bf16(al, Bh[ks][1], acc[i][1], 0, 0, 0);
            acc[i][1] = __builtin_amdgcn_mfma_f32_16x16x32_bf16(ah, Bl[ks][1], acc[i][1], 0, 0, 0);
        }
    }

    // ---- epilogue: +qb, relu, *W2, reduce over h ----
    // C/D layout: col(h) = l15, row(a) = i*16 + quad*4 + reg
    float p[4][4];
    #pragma unroll
    for (int i = 0; i < 4; i++)
        #pragma unroll
        for (int r = 0; r < 4; r++) p[i][r] = 0.f;
    #pragma unroll
    for (int j = 0; j < 2; j++) {
        int h = wave * 32 + j * 16 + l15;
        float qbv = qb_s[h], w2v = w2_s[h];
        #pragma unroll
        for (int i = 0; i < 4; i++)
            #pragma unroll
            for (int r = 0; r < 4; r++) {
                float v = acc[i][j][r] + qbv;
                v = v > 0.f ? v : 0.f;
                p[i][r] += v * w2v;
            }
    }
    #pragma unroll
    for (int m = 1; m <= 8; m <<= 1)
        #pragma unroll
        for (int i = 0; i < 4; i++)
            #pragma unroll
            for (int r = 0; r < 4; r++)
                p[i][r] += __shfl_xor(p[i][r], m);
    if (l15 == 0) {
        #pragma unroll
        for (int i = 0; i < 4; i++)
            #pragma unroll
            for (int r = 0; r < 4; r++)
                part2[i * 16 + quad * 4 + r][wave] = p[i][r];
    }
    __syncthreads();

    // ---- softmax numerator ----
    if (t < 64) {
        float sum = part2[t][0] + part2[t][1] + part2[t][2] + part2[t][3] + b2v;
        float logit = sum / tval;
        float e = (mytag > 0) ? __expf(logit) : 0.f;
        e_s[t] = e;
        float zs = e;
        #pragma unroll
        for (int off = 32; off > 0; off >>= 1) zs += __shfl_down(zs, off);
        if (t == 0) atomicAdd(&Zsum[bn], zs);
    }
    __syncthreads();

    // ---- phase 3: out_acc[bn,o] += sum_a e[a] * att1[a,o]  (L2-hot) ----
    const int o = t & 127;
    const int half = t >> 7;
    const float* ab = att_base + (size_t)(half * 32) * Oc + o;
    float accum = 0.f;
    #pragma unroll 8
    for (int a = 0; a < 32; a++)
        accum += e_s[half * 32 + a] * ab[(size_t)a * Oc];
    atomicAdd(&out_acc[bn * Oc + o], accum);
}

// ---------------------------------------------------------------------------
__global__ void finalize_kernel(const float* __restrict__ out_acc,
                                const float* __restrict__ Zsum,
                                float* __restrict__ out)
{
    int idx = blockIdx.x * 256 + threadIdx.x;
    if (idx < BN * Oc) {
        out[idx] = out_acc[idx] / Zsum[idx >> 7];
    }
}

extern "C" void kernel_launch(void* const* d_in, const int* in_sizes, int n_in,
                              void* d_out, int out_size, void* d_ws, size_t ws_size,
                              hipStream_t stream)
{
    (void)in_sizes; (void)n_in; (void)out_size; (void)ws_size;

    const float* q    = (const float*)d_in[0];
    const float* att1 = (const float*)d_in[1];
    const float* obj  = (const float*)d_in[2];
    const int*   tags = (const int*)d_in[3];
    const float* W1   = (const float*)d_in[4];
    const float* b1   = (const float*)d_in[5];
    const float* W2   = (const float*)d_in[6];
    const float* b2   = (const float*)d_in[7];
    const void*  tptr = d_in[8];
    float* out = (float*)d_out;

    char* wsb = (char*)d_ws;
    unsigned short* Mt_hi = (unsigned short*)wsb;                          // 2 MB
    unsigned short* Mt_lo = (unsigned short*)(wsb + (size_t)2*1024*1024);  // 2 MB
    float* qbuf = (float*)(wsb + (size_t)4*1024*1024);   // BN*H  = 32768 floats
    float* oacc = qbuf + (size_t)BN * Hc;                // BN*O  = 32768
    float* Zs   = oacc + (size_t)BN * Oc;                // BN    = 256

    prep_M_kernel<<<dim3(4, 2, Bc), 256, 0, stream>>>(obj, W1, Mt_hi, Mt_lo);
    prep_qb_kernel<<<dim3(BN), 512, 0, stream>>>(q, W1, b1, qbuf, oacc, Zs);
    main_kernel<<<dim3(Ac / 64, Nc, Bc), 256, 0, stream>>>(att1, tags, Mt_hi, Mt_lo,
                                                           qbuf, W2, b2, tptr, oacc, Zs);
    finalize_kernel<<<dim3(BN * Oc / 256), 256, 0, stream>>>(oacc, Zs, out);
}

// Round 4
// 250.131 us; speedup vs baseline: 1.2738x; 1.0177x over previous
//
#include <hip/hip_runtime.h>
#include <math.h>

#define Bc 64
#define Nc 4
#define Ac 1024
#define Oc 128
#define Dc 256
#define Qc 256
#define Hc 128
#define BN (Bc*Nc)

using f4     = __attribute__((ext_vector_type(4))) float;
using f32x4  = __attribute__((ext_vector_type(4))) float;
using short8 = __attribute__((ext_vector_type(8))) short;
using us4    = __attribute__((ext_vector_type(4))) unsigned short;

__device__ inline float decode_t(const void* p) {
    int i = *(const int*)p;
    if (i >= 1 && i <= 1000000) return (float)i;
    return __int_as_float(i);
}

// round-to-nearest-even fp32 -> bf16
__device__ inline unsigned short bf16_rne(float x) {
    unsigned u = __builtin_bit_cast(unsigned, x);
    u += 0x7FFFu + ((u >> 16) & 1u);
    return (unsigned short)(u >> 16);
}

// split fp32 -> truncated bf16 hi + bf16(residual) lo.  x ~= hi + lo, err ~2^-16
__device__ inline void split_bf16(float x, unsigned short& hi, unsigned short& lo) {
    unsigned u = __builtin_bit_cast(unsigned, x);
    hi = (unsigned short)(u >> 16);
    float hif = __builtin_bit_cast(float, u & 0xFFFF0000u);
    float lof = x - hif;
    lo = (unsigned short)(__builtin_bit_cast(unsigned, lof) >> 16);
}

// ---------------------------------------------------------------------------
// prep_M: Mt[b][h][o] = sum_d W1[d][h] * obj[b][o][d]  (transposed, [n][k])
// bf16 hi/lo output. grid (4,2,64): 32h x 64o tile, 256 thr, 2x4 reg block.
// K-loop double-buffered: loads for chunk ko+1 issued before compute of ko.
// ---------------------------------------------------------------------------
__global__ __launch_bounds__(256) void prep_M_kernel(
    const float* __restrict__ obj, const float* __restrict__ W1,
    unsigned short* __restrict__ Mt_hi, unsigned short* __restrict__ Mt_lo)
{
    __shared__ float w_s[32][36];     // [k][h]
    __shared__ float obj_sT[32][68];  // [k][o]

    const int t  = threadIdx.x;
    const int tx = t & 15;    // o = o0 + tx*4 + j
    const int ty = t >> 4;    // h = h0 + ty*2 + i
    const int h0 = blockIdx.x * 32;
    const int o0 = blockIdx.y * 64;
    const int b  = blockIdx.z;
    const int r8 = t >> 3, c8 = t & 7;

    const float* objb = obj + ((size_t)b * Oc + o0) * Dc;

    float acc[2][4];
    #pragma unroll
    for (int i = 0; i < 2; i++)
        #pragma unroll
        for (int j = 0; j < 4; j++) acc[i][j] = 0.f;

    // prefetch chunk 0
    f4 wv  = *(const f4*)(W1 + (size_t)r8 * Hc + h0 + c8 * 4);
    f4 ov0 = *(const f4*)(objb + (size_t)r8 * Dc + c8 * 4);
    f4 ov1 = *(const f4*)(objb + (size_t)(r8 + 32) * Dc + c8 * 4);

    for (int ko = 0; ko < 8; ++ko) {
        // commit prefetched regs to LDS
        *(f4*)&w_s[r8][c8 * 4] = wv;
        obj_sT[c8 * 4 + 0][r8] = ov0[0];
        obj_sT[c8 * 4 + 1][r8] = ov0[1];
        obj_sT[c8 * 4 + 2][r8] = ov0[2];
        obj_sT[c8 * 4 + 3][r8] = ov0[3];
        obj_sT[c8 * 4 + 0][r8 + 32] = ov1[0];
        obj_sT[c8 * 4 + 1][r8 + 32] = ov1[1];
        obj_sT[c8 * 4 + 2][r8 + 32] = ov1[2];
        obj_sT[c8 * 4 + 3][r8 + 32] = ov1[3];
        __syncthreads();
        // issue next chunk's loads (in flight during compute)
        if (ko < 7) {
            wv  = *(const f4*)(W1 + (size_t)((ko + 1) * 32 + r8) * Hc + h0 + c8 * 4);
            ov0 = *(const f4*)(objb + (size_t)r8 * Dc + (ko + 1) * 32 + c8 * 4);
            ov1 = *(const f4*)(objb + (size_t)(r8 + 32) * Dc + (ko + 1) * 32 + c8 * 4);
        }
        #pragma unroll 4
        for (int k = 0; k < 32; k++) {
            float a0 = w_s[k][ty * 2];
            float a1 = w_s[k][ty * 2 + 1];
            f4 bv = *(const f4*)&obj_sT[k][tx * 4];
            #pragma unroll
            for (int j = 0; j < 4; j++) {
                acc[0][j] += a0 * bv[j];
                acc[1][j] += a1 * bv[j];
            }
        }
        __syncthreads();
    }

    #pragma unroll
    for (int i = 0; i < 2; i++) {
        us4 hi, lo;
        #pragma unroll
        for (int j = 0; j < 4; j++) {
            unsigned short h16, l16;
            split_bf16(acc[i][j], h16, l16);
            hi[j] = h16; lo[j] = l16;
        }
        size_t ofs = ((size_t)b * Hc + h0 + ty * 2 + i) * Oc + o0 + tx * 4;
        *(us4*)(Mt_hi + ofs) = hi;
        *(us4*)(Mt_lo + ofs) = lo;
    }
}

// ---------------------------------------------------------------------------
// prep_qb: qb[bn,h] = q[bn,:] @ W1q + b1[h]; zero-init out_acc and Z
// ---------------------------------------------------------------------------
__global__ __launch_bounds__(512) void prep_qb_kernel(
    const float* __restrict__ q, const float* __restrict__ W1,
    const float* __restrict__ b1, float* __restrict__ qb,
    float* __restrict__ out_acc, float* __restrict__ Zsum)
{
    __shared__ float qs[256];
    __shared__ float red[4][128];
    const int t = threadIdx.x;
    const int bn = blockIdx.x;

    if (t < 256) qs[t] = q[bn * Qc + t];
    __syncthreads();

    const int h = t & 127, kq = t >> 7;
    float acc = 0.f;
    const float* w = W1 + (size_t)(Dc + kq * 64) * Hc + h;
    #pragma unroll 8
    for (int d = 0; d < 64; ++d)
        acc += qs[kq * 64 + d] * w[(size_t)d * Hc];
    red[kq][h] = acc;
    __syncthreads();

    if (t < 128) {
        qb[bn * Hc + t] = b1[t] + red[0][t] + red[1][t] + red[2][t] + red[3][t];
        out_acc[bn * Oc + t] = 0.f;
    }
    if (t == 128) Zsum[bn] = 0.f;
}

// ---------------------------------------------------------------------------
// main: grid (8,4,64), 512 thr (8 waves). Each block: 2 a-tiles of 64,
// software-pipelined (tile1 staging loads in flight during tile0 compute).
// Per tile: preact = att_tile @ M (A=RNE bf16, B=hi/lo split -> 2 MFMA),
// relu+W2 -> logits -> masked exp -> Z atomic -> out_acc atomic.
// Wave w covers h = w*16..w*16+15 for all 64 a-rows.
// ---------------------------------------------------------------------------
__global__ __launch_bounds__(512, 3) void main_kernel(
    const float* __restrict__ att1, const int* __restrict__ tags,
    const unsigned short* __restrict__ Mt_hi, const unsigned short* __restrict__ Mt_lo,
    const float* __restrict__ qb, const float* __restrict__ W2,
    const float* __restrict__ b2, const void* __restrict__ tptr,
    float* __restrict__ out_acc, float* __restrict__ Zsum)
{
    __shared__ unsigned short A_s[2][64][136];  // [tile][a][o] bf16
    __shared__ float part2[64][9];              // +1 pad: conflict-free reduce
    __shared__ float qb_s[128], w2_s[128];
    __shared__ float e_s[64];

    const int t    = threadIdx.x;
    const int wave = t >> 6;         // 0..7
    const int lane = t & 63;
    const int l15  = lane & 15;
    const int quad = lane >> 4;
    const int a0 = blockIdx.x * 128;
    const int n  = blockIdx.y;
    const int b  = blockIdx.z;
    const int bn = b * Nc + n;

    const float* att_base = att1 + ((size_t)bn * Ac + a0) * Oc;

    // ---- stage tile0 (HBM), issued first ----
    f4 sv[4];
    #pragma unroll
    for (int s = 0; s < 4; s++) {
        int idx = t + 512 * s;
        sv[s] = *(const f4*)(att_base + (size_t)(idx >> 5) * Oc + (idx & 31) * 4);
    }

    // ---- B fragments (L2-hot Mt): h-row = wave*16 + l15 ----
    const size_t brow = ((size_t)b * Hc + wave * 16 + l15) * Oc;
    short8 Bh[4], Bl[4];
    #pragma unroll
    for (int ks = 0; ks < 4; ks++) {
        const int ko = ks * 32 + quad * 8;
        Bh[ks] = *(const short8*)(Mt_hi + brow + ko);
        Bl[ks] = *(const short8*)(Mt_lo + brow + ko);
    }

    if (t < 128) { qb_s[t] = qb[bn * Hc + t]; w2_s[t] = W2[t]; }
    const int tag0 = (t < 64) ? tags[bn * Ac + a0 + t] : 0;
    const int tag1 = (t < 64) ? tags[bn * Ac + a0 + 64 + t] : 0;
    const float b2v  = b2[0];
    const float tval = decode_t(tptr);

    #pragma unroll
    for (int tile = 0; tile < 2; ++tile) {
        // ---- convert staged fp32 -> bf16 (RNE) into LDS ----
        #pragma unroll
        for (int s = 0; s < 4; s++) {
            int idx = t + 512 * s;
            int r = idx >> 5, c4 = idx & 31;
            us4 h4;
            #pragma unroll
            for (int j = 0; j < 4; j++) h4[j] = bf16_rne(sv[s][j]);
            *(us4*)&A_s[tile][r][c4 * 4] = h4;
        }
        __syncthreads();

        // ---- issue tile1 staging now; in flight during tile0 compute ----
        if (tile == 0) {
            #pragma unroll
            for (int s = 0; s < 4; s++) {
                int idx = t + 512 * s;
                sv[s] = *(const f4*)(att_base + (size_t)(64 + (idx >> 5)) * Oc + (idx & 31) * 4);
            }
        }

        // ---- MFMA: 2 products (A_rne * Bhi + A_rne * Blo) ----
        f32x4 acc[4];
        #pragma unroll
        for (int i = 0; i < 4; i++) acc[i] = (f32x4)(0.f);
        #pragma unroll
        for (int ks = 0; ks < 4; ks++) {
            const int ko = ks * 32 + quad * 8;
            #pragma unroll
            for (int i = 0; i < 4; i++) {
                short8 ah = *(const short8*)&A_s[tile][i * 16 + l15][ko];
                acc[i] = __builtin_amdgcn_mfma_f32_16x16x32_bf16(ah, Bh[ks], acc[i], 0, 0, 0);
                acc[i] = __builtin_amdgcn_mfma_f32_16x16x32_bf16(ah, Bl[ks], acc[i], 0, 0, 0);
            }
        }

        // ---- epilogue: +qb, relu, *W2, reduce over h ----
        // C/D layout: col(h within wave-tile) = l15, row(a) = i*16 + quad*4 + r
        const int h = wave * 16 + l15;
        const float qbv = qb_s[h], w2v = w2_s[h];
        float p[4][4];
        #pragma unroll
        for (int i = 0; i < 4; i++)
            #pragma unroll
            for (int r = 0; r < 4; r++) {
                float v = acc[i][r] + qbv;
                v = v > 0.f ? v : 0.f;
                p[i][r] = v * w2v;
            }
        #pragma unroll
        for (int m = 1; m <= 8; m <<= 1)
            #pragma unroll
            for (int i = 0; i < 4; i++)
                #pragma unroll
                for (int r = 0; r < 4; r++)
                    p[i][r] += __shfl_xor(p[i][r], m);
        if (l15 == 0) {
            #pragma unroll
            for (int i = 0; i < 4; i++)
                #pragma unroll
                for (int r = 0; r < 4; r++)
                    part2[i * 16 + quad * 4 + r][wave] = p[i][r];
        }
        __syncthreads();

        // ---- softmax numerator ----
        if (t < 64) {
            float sum = b2v;
            #pragma unroll
            for (int x = 0; x < 8; x++) sum += part2[t][x];
            float logit = sum / tval;
            int tg = tile ? tag1 : tag0;
            float e = (tg > 0) ? __expf(logit) : 0.f;
            e_s[t] = e;
            float zs = e;
            #pragma unroll
            for (int off = 32; off > 0; off >>= 1) zs += __shfl_down(zs, off);
            if (t == 0) atomicAdd(&Zsum[bn], zs);
        }
        __syncthreads();

        // ---- phase 3: out_acc[bn,o] += sum_a e[a]*att1[a,o] (L2-hot) ----
        const int o  = t & 127;
        const int q4 = t >> 7;   // 0..3, 16 a-rows each
        const float* ab = att_base + ((size_t)tile * 64 + q4 * 16) * Oc + o;
        float accum = 0.f;
        #pragma unroll
        for (int a = 0; a < 16; a++)
            accum += e_s[q4 * 16 + a] * ab[(size_t)a * Oc];
        atomicAdd(&out_acc[bn * Oc + o], accum);
        // e_s/part2 reuse in tile1 is protected by the two barriers above
    }
}

// ---------------------------------------------------------------------------
__global__ void finalize_kernel(const float* __restrict__ out_acc,
                                const float* __restrict__ Zsum,
                                float* __restrict__ out)
{
    int idx = blockIdx.x * 256 + threadIdx.x;
    if (idx < BN * Oc) {
        out[idx] = out_acc[idx] / Zsum[idx >> 7];
    }
}

extern "C" void kernel_launch(void* const* d_in, const int* in_sizes, int n_in,
                              void* d_out, int out_size, void* d_ws, size_t ws_size,
                              hipStream_t stream)
{
    (void)in_sizes; (void)n_in; (void)out_size; (void)ws_size;

    const float* q    = (const float*)d_in[0];
    const float* att1 = (const float*)d_in[1];
    const float* obj  = (const float*)d_in[2];
    const int*   tags = (const int*)d_in[3];
    const float* W1   = (const float*)d_in[4];
    const float* b1   = (const float*)d_in[5];
    const float* W2   = (const float*)d_in[6];
    const float* b2   = (const float*)d_in[7];
    const void*  tptr = d_in[8];
    float* out = (float*)d_out;

    char* wsb = (char*)d_ws;
    unsigned short* Mt_hi = (unsigned short*)wsb;                          // 2 MB
    unsigned short* Mt_lo = (unsigned short*)(wsb + (size_t)2*1024*1024);  // 2 MB
    float* qbuf = (float*)(wsb + (size_t)4*1024*1024);   // BN*H  = 32768 floats
    float* oacc = qbuf + (size_t)BN * Hc;                // BN*O  = 32768
    float* Zs   = oacc + (size_t)BN * Oc;                // BN    = 256

    prep_M_kernel<<<dim3(4, 2, Bc), 256, 0, stream>>>(obj, W1, Mt_hi, Mt_lo);
    prep_qb_kernel<<<dim3(BN), 512, 0, stream>>>(q, W1, b1, qbuf, oacc, Zs);
    main_kernel<<<dim3(Ac / 128, Nc, Bc), 512, 0, stream>>>(att1, tags, Mt_hi, Mt_lo,
                                                            qbuf, W2, b2, tptr, oacc, Zs);
    finalize_kernel<<<dim3(BN * Oc / 256), 256, 0, stream>>>(oacc, Zs, out);
}

// Round 5
// 248.740 us; speedup vs baseline: 1.2809x; 1.0056x over previous
//
#include <hip/hip_runtime.h>
#include <math.h>

#define Bc 64
#define Nc 4
#define Ac 1024
#define Oc 128
#define Dc 256
#define Qc 256
#define Hc 128
#define BN (Bc*Nc)

using f4     = __attribute__((ext_vector_type(4))) float;
using f32x4  = __attribute__((ext_vector_type(4))) float;
using short8 = __attribute__((ext_vector_type(8))) short;
using us4    = __attribute__((ext_vector_type(4))) unsigned short;

__device__ inline float decode_t(const void* p) {
    int i = *(const int*)p;
    if (i >= 1 && i <= 1000000) return (float)i;
    return __int_as_float(i);
}

// round-to-nearest-even fp32 -> bf16
__device__ inline unsigned short bf16_rne(float x) {
    unsigned u = __builtin_bit_cast(unsigned, x);
    u += 0x7FFFu + ((u >> 16) & 1u);
    return (unsigned short)(u >> 16);
}

// split fp32 -> truncated bf16 hi + bf16(residual) lo.  x ~= hi + lo
__device__ inline void split_bf16(float x, unsigned short& hi, unsigned short& lo) {
    unsigned u = __builtin_bit_cast(unsigned, x);
    hi = (unsigned short)(u >> 16);
    float hif = __builtin_bit_cast(float, u & 0xFFFF0000u);
    float lof = x - hif;
    lo = (unsigned short)(__builtin_bit_cast(unsigned, lof) >> 16);
}

// ---------------------------------------------------------------------------
// prep_M: Mt[b][h][o] = sum_d W1[d][h] * obj[b][o][d]  (transposed, [n][k])
// bf16 hi/lo output. grid (4,2,64): 32h x 64o tile, 256 thr, double-buffered K.
// ---------------------------------------------------------------------------
__global__ __launch_bounds__(256) void prep_M_kernel(
    const float* __restrict__ obj, const float* __restrict__ W1,
    unsigned short* __restrict__ Mt_hi, unsigned short* __restrict__ Mt_lo)
{
    __shared__ float w_s[32][36];     // [k][h]
    __shared__ float obj_sT[32][68];  // [k][o]

    const int t  = threadIdx.x;
    const int tx = t & 15;    // o = o0 + tx*4 + j
    const int ty = t >> 4;    // h = h0 + ty*2 + i
    const int h0 = blockIdx.x * 32;
    const int o0 = blockIdx.y * 64;
    const int b  = blockIdx.z;
    const int r8 = t >> 3, c8 = t & 7;

    const float* objb = obj + ((size_t)b * Oc + o0) * Dc;

    float acc[2][4];
    #pragma unroll
    for (int i = 0; i < 2; i++)
        #pragma unroll
        for (int j = 0; j < 4; j++) acc[i][j] = 0.f;

    f4 wv  = *(const f4*)(W1 + (size_t)r8 * Hc + h0 + c8 * 4);
    f4 ov0 = *(const f4*)(objb + (size_t)r8 * Dc + c8 * 4);
    f4 ov1 = *(const f4*)(objb + (size_t)(r8 + 32) * Dc + c8 * 4);

    for (int ko = 0; ko < 8; ++ko) {
        *(f4*)&w_s[r8][c8 * 4] = wv;
        obj_sT[c8 * 4 + 0][r8] = ov0[0];
        obj_sT[c8 * 4 + 1][r8] = ov0[1];
        obj_sT[c8 * 4 + 2][r8] = ov0[2];
        obj_sT[c8 * 4 + 3][r8] = ov0[3];
        obj_sT[c8 * 4 + 0][r8 + 32] = ov1[0];
        obj_sT[c8 * 4 + 1][r8 + 32] = ov1[1];
        obj_sT[c8 * 4 + 2][r8 + 32] = ov1[2];
        obj_sT[c8 * 4 + 3][r8 + 32] = ov1[3];
        __syncthreads();
        if (ko < 7) {
            wv  = *(const f4*)(W1 + (size_t)((ko + 1) * 32 + r8) * Hc + h0 + c8 * 4);
            ov0 = *(const f4*)(objb + (size_t)r8 * Dc + (ko + 1) * 32 + c8 * 4);
            ov1 = *(const f4*)(objb + (size_t)(r8 + 32) * Dc + (ko + 1) * 32 + c8 * 4);
        }
        #pragma unroll 4
        for (int k = 0; k < 32; k++) {
            float a0 = w_s[k][ty * 2];
            float a1 = w_s[k][ty * 2 + 1];
            f4 bv = *(const f4*)&obj_sT[k][tx * 4];
            #pragma unroll
            for (int j = 0; j < 4; j++) {
                acc[0][j] += a0 * bv[j];
                acc[1][j] += a1 * bv[j];
            }
        }
        __syncthreads();
    }

    #pragma unroll
    for (int i = 0; i < 2; i++) {
        us4 hi, lo;
        #pragma unroll
        for (int j = 0; j < 4; j++) {
            unsigned short h16, l16;
            split_bf16(acc[i][j], h16, l16);
            hi[j] = h16; lo[j] = l16;
        }
        size_t ofs = ((size_t)b * Hc + h0 + ty * 2 + i) * Oc + o0 + tx * 4;
        *(us4*)(Mt_hi + ofs) = hi;
        *(us4*)(Mt_lo + ofs) = lo;
    }
}

// ---------------------------------------------------------------------------
// prep_qb: qb[bn,h] = q[bn,:] @ W1q + b1[h]
// ---------------------------------------------------------------------------
__global__ __launch_bounds__(512) void prep_qb_kernel(
    const float* __restrict__ q, const float* __restrict__ W1,
    const float* __restrict__ b1, float* __restrict__ qb)
{
    __shared__ float qs[256];
    __shared__ float red[4][128];
    const int t = threadIdx.x;
    const int bn = blockIdx.x;

    if (t < 256) qs[t] = q[bn * Qc + t];
    __syncthreads();

    const int h = t & 127, kq = t >> 7;
    float acc = 0.f;
    const float* w = W1 + (size_t)(Dc + kq * 64) * Hc + h;
    #pragma unroll 8
    for (int d = 0; d < 64; ++d)
        acc += qs[kq * 64 + d] * w[(size_t)d * Hc];
    red[kq][h] = acc;
    __syncthreads();

    if (t < 128)
        qb[bn * Hc + t] = b1[t] + red[0][t] + red[1][t] + red[2][t] + red[3][t];
}

// ---------------------------------------------------------------------------
// main: persistent block per bn. grid (256), 1024 thr (16 waves), 1 block/CU.
// Streams 8 a-tiles of 128 rows; ping-pong bf16 A in LDS, depth-1 register
// prefetch of the next tile's fp32 staging loads. No global atomics:
// Z and out accumulate locally; block writes its own 128 outputs at the end.
// Wave w: rows (w>>3)*64 + i*16 (i=0..3), h-cols (w&7)*16.
// ---------------------------------------------------------------------------
__global__ __launch_bounds__(1024, 4) void main_kernel(
    const float* __restrict__ att1, const int* __restrict__ tags,
    const unsigned short* __restrict__ Mt_hi, const unsigned short* __restrict__ Mt_lo,
    const float* __restrict__ qb, const float* __restrict__ W2,
    const float* __restrict__ b2, const void* __restrict__ tptr,
    float* __restrict__ out)
{
    __shared__ unsigned short A_s[2][128][136];  // ping-pong bf16 tiles, 69.6 KB
    __shared__ float part2[128][9];              // logit partials, +1 pad
    __shared__ float part3[8][132];              // phase-3 partials
    __shared__ float e_s[128];
    __shared__ float qb_s[128], w2_s[128];
    __shared__ float zfin[2];

    const int t    = threadIdx.x;
    const int wave = t >> 6;          // 0..15
    const int lane = t & 63;
    const int l15  = lane & 15;
    const int quad = lane >> 4;
    const int bn = blockIdx.x;
    const int b  = bn >> 2;
    const int rowg = (wave >> 3) * 64;   // 0 or 64
    const int hw   = (wave & 7) * 16;    // h-group base

    const float* att_bn = att1 + (size_t)bn * Ac * Oc;

    // ---- prologue: tile-0 staging loads (HBM) ----
    f4 sv[4];
    #pragma unroll
    for (int s = 0; s < 4; s++) {
        int idx = t + 1024 * s;
        sv[s] = *(const f4*)(att_bn + (size_t)idx * 4);
    }

    // ---- B fragments (hi/lo), once per block ----
    const size_t brow = ((size_t)b * Hc + hw + l15) * Oc;
    short8 Bh[4], Bl[4];
    #pragma unroll
    for (int ks = 0; ks < 4; ks++) {
        const int ko = ks * 32 + quad * 8;
        Bh[ks] = *(const short8*)(Mt_hi + brow + ko);
        Bl[ks] = *(const short8*)(Mt_lo + brow + ko);
    }

    if (t < 128) { qb_s[t] = qb[bn * Hc + t]; w2_s[t] = W2[t]; }
    int tg_cur = (t < 128) ? tags[(size_t)bn * Ac + t] : 0;
    const float b2v  = b2[0];
    const float tval = decode_t(tptr);

    float z_reg = 0.f, out_reg = 0.f;

    for (int tile = 0; tile < 8; ++tile) {
        const int buf = tile & 1;
        const float* tile_ptr = att_bn + (size_t)tile * 128 * Oc;

        // ---- convert staged fp32 -> bf16 RNE into LDS ----
        #pragma unroll
        for (int s = 0; s < 4; s++) {
            int idx = t + 1024 * s;
            int r = idx >> 5, c4 = idx & 31;
            us4 h4;
            #pragma unroll
            for (int j = 0; j < 4; j++) h4[j] = bf16_rne(sv[s][j]);
            *(us4*)&A_s[buf][r][c4 * 4] = h4;
        }
        __syncthreads();

        // ---- prefetch next tile (in flight through all of this tile) ----
        int tg_next = 0;
        if (tile < 7) {
            const float* np = att_bn + (size_t)(tile + 1) * 128 * Oc;
            #pragma unroll
            for (int s = 0; s < 4; s++) {
                int idx = t + 1024 * s;
                sv[s] = *(const f4*)(np + (size_t)idx * 4);
            }
            if (t < 128) tg_next = tags[(size_t)bn * Ac + (tile + 1) * 128 + t];
        }

        // ---- MFMA: A_rne * (Bhi + Blo) ----
        f32x4 acc[4];
        #pragma unroll
        for (int i = 0; i < 4; i++) acc[i] = (f32x4)(0.f);
        #pragma unroll
        for (int ks = 0; ks < 4; ks++) {
            const int ko = ks * 32 + quad * 8;
            #pragma unroll
            for (int i = 0; i < 4; i++) {
                short8 ah = *(const short8*)&A_s[buf][rowg + i * 16 + l15][ko];
                acc[i] = __builtin_amdgcn_mfma_f32_16x16x32_bf16(ah, Bh[ks], acc[i], 0, 0, 0);
                acc[i] = __builtin_amdgcn_mfma_f32_16x16x32_bf16(ah, Bl[ks], acc[i], 0, 0, 0);
            }
        }

        // ---- epilogue: +qb, relu, *W2, reduce over the wave's 16 h ----
        // C/D layout: col(h) = l15, row(a) = rowg + i*16 + quad*4 + r
        {
            const float qbv = qb_s[hw + l15], w2v = w2_s[hw + l15];
            float p[4][4];
            #pragma unroll
            for (int i = 0; i < 4; i++)
                #pragma unroll
                for (int r = 0; r < 4; r++) {
                    float v = acc[i][r] + qbv;
                    v = v > 0.f ? v : 0.f;
                    p[i][r] = v * w2v;
                }
            #pragma unroll
            for (int m = 1; m <= 8; m <<= 1)
                #pragma unroll
                for (int i = 0; i < 4; i++)
                    #pragma unroll
                    for (int r = 0; r < 4; r++)
                        p[i][r] += __shfl_xor(p[i][r], m);
            if (l15 == 0) {
                #pragma unroll
                for (int i = 0; i < 4; i++)
                    #pragma unroll
                    for (int r = 0; r < 4; r++)
                        part2[rowg + i * 16 + quad * 4 + r][wave & 7] = p[i][r];
            }
        }
        __syncthreads();

        // ---- masked exp; accumulate Z in registers ----
        if (t < 128) {
            float sum = b2v;
            #pragma unroll
            for (int x = 0; x < 8; x++) sum += part2[t][x];
            float logit = sum / tval;
            float e = (tg_cur > 0) ? __expf(logit) : 0.f;
            e_s[t] = e;
            z_reg += e;
        }
        __syncthreads();

        // ---- phase 3: partial out[o] += sum_a e[a]*att1[a,o]  (L2-hot) ----
        {
            const int o  = t & 127;
            const int g  = t >> 7;   // 0..7, 16 rows each
            const float* ab = tile_ptr + (size_t)(g * 16) * Oc + o;
            float accum = 0.f;
            #pragma unroll
            for (int a = 0; a < 16; a++)
                accum += e_s[g * 16 + a] * ab[(size_t)a * Oc];
            part3[g][o] = accum;
        }
        __syncthreads();

        if (t < 128) {
            float s = 0.f;
            #pragma unroll
            for (int g = 0; g < 8; g++) s += part3[g][t];
            out_reg += s;
        }
        tg_cur = tg_next;
    }

    // ---- finalize: reduce Z across waves 0-1, write output ----
    __syncthreads();
    if (t < 128) {
        float z = z_reg;
        #pragma unroll
        for (int off = 32; off > 0; off >>= 1) z += __shfl_down(z, off);
        if (lane == 0) zfin[wave] = z;
    }
    __syncthreads();
    if (t < 128) {
        float Z = zfin[0] + zfin[1];
        out[(size_t)bn * Oc + t] = out_reg / Z;
    }
}

extern "C" void kernel_launch(void* const* d_in, const int* in_sizes, int n_in,
                              void* d_out, int out_size, void* d_ws, size_t ws_size,
                              hipStream_t stream)
{
    (void)in_sizes; (void)n_in; (void)out_size; (void)ws_size;

    const float* q    = (const float*)d_in[0];
    const float* att1 = (const float*)d_in[1];
    const float* obj  = (const float*)d_in[2];
    const int*   tags = (const int*)d_in[3];
    const float* W1   = (const float*)d_in[4];
    const float* b1   = (const float*)d_in[5];
    const float* W2   = (const float*)d_in[6];
    const float* b2   = (const float*)d_in[7];
    const void*  tptr = d_in[8];
    float* out = (float*)d_out;

    char* wsb = (char*)d_ws;
    unsigned short* Mt_hi = (unsigned short*)wsb;                          // 2 MB
    unsigned short* Mt_lo = (unsigned short*)(wsb + (size_t)2*1024*1024);  // 2 MB
    float* qbuf = (float*)(wsb + (size_t)4*1024*1024);   // BN*H floats

    prep_M_kernel<<<dim3(4, 2, Bc), 256, 0, stream>>>(obj, W1, Mt_hi, Mt_lo);
    prep_qb_kernel<<<dim3(BN), 512, 0, stream>>>(q, W1, b1, qbuf);
    main_kernel<<<dim3(BN), 1024, 0, stream>>>(att1, tags, Mt_hi, Mt_lo,
                                               qbuf, W2, b2, tptr, out);
}